// Round 12
// baseline (456.654 us; speedup 1.0000x reference)
//
#include <hip/hip_runtime.h>
#include <hip/hip_bf16.h>

#define NN 50000
#define NE 800000
#define NG 64
#define NBUCK 256
#define BN 196        // nodes per bucket; 256*196 = 50176 >= NN
#define EPB 4096      // edges per binning block
#define HB 196        // ceil(NE/EPB)
#define SMAX 4200     // per-bucket segment capacity (mean 3136, sigma 56)

typedef __attribute__((ext_vector_type(8))) short short8;
typedef __attribute__((ext_vector_type(4))) float float4v;
typedef __attribute__((ext_vector_type(2))) float float2v;

__device__ __forceinline__ float bf2f(unsigned short u){
    unsigned v = ((unsigned)u) << 16; float f; __builtin_memcpy(&f, &v, 4); return f;
}
__device__ __forceinline__ unsigned short f2bf(float f){
    unsigned u; __builtin_memcpy(&u, &f, 4);
    u = (u + 0x7fffu + ((u >> 16) & 1u)) >> 16;
    return (unsigned short)u;
}
__device__ __forceinline__ float lrelu(float v){ return v > 0.f ? v : 0.2f * v; }

__device__ __forceinline__ float ldflex(const void* p, long i, int isbf){
    if (isbf) return bf2f(((const unsigned short*)p)[i]);
    return ((const float*)p)[i];
}
__device__ __forceinline__ int ldidx(const int* p, long i, int is64){
    return p[is64 ? (i << 1) : i];
}

// ---- fp8 e4m3fn (OCP) pack/unpack, HW cvt when available ----
__device__ __forceinline__ unsigned int enc_fp8_1(float f){
    unsigned u; __builtin_memcpy(&u, &f, 4);
    unsigned s = (u >> 24) & 0x80u;
    float a = fabsf(f); a = fminf(a, 448.f);
    float x = a * 0x1p-120f;
    unsigned xu; __builtin_memcpy(&xu, &x, 4);
    unsigned r = (xu + 0x7FFFFu + ((xu >> 20) & 1u)) >> 20;
    if (r > 0x7Eu) r = 0x7Eu;
    return s | r;
}
__device__ __forceinline__ unsigned short pk_fp8(float a, float b){
#if __has_builtin(__builtin_amdgcn_cvt_pk_fp8_f32)
    int r = __builtin_amdgcn_cvt_pk_fp8_f32(a, b, 0, false);
    return (unsigned short)(r & 0xFFFF);
#else
    return (unsigned short)(enc_fp8_1(a) | (enc_fp8_1(b) << 8));
#endif
}
__device__ __forceinline__ float dec_fp8_manual(unsigned int byte){
    unsigned bits = ((byte & 0x80u) << 24) | ((byte & 0x7Fu) << 20);
    float f; __builtin_memcpy(&f, &bits, 4);
    return f * 0x1p120f;
}
__device__ __forceinline__ void dec_fp8x4_pk(unsigned int v, float2v& lo, float2v& hi){
#if __has_builtin(__builtin_amdgcn_cvt_pk_f32_fp8)
    lo = __builtin_amdgcn_cvt_pk_f32_fp8((int)v, false);
    hi = __builtin_amdgcn_cvt_pk_f32_fp8((int)v, true);
#else
    lo[0] = dec_fp8_manual(v & 0xFF);
    lo[1] = dec_fp8_manual((v >> 8) & 0xFF);
    hi[0] = dec_fp8_manual((v >> 16) & 0xFF);
    hi[1] = dec_fp8_manual((v >> 24) & 0xFF);
#endif
}

__device__ __forceinline__ float rdlane_f(float v, int l){
    int i; __builtin_memcpy(&i, &v, 4);
    int r = __builtin_amdgcn_readlane(i, l);
    float f; __builtin_memcpy(&f, &r, 4);
    return f;
}

// ---------------- runtime dtype detection + bcnt zero ----------------
__global__ void detect_kernel(const unsigned short* xu, const unsigned int* eiu,
                              const unsigned int* bu, int* flags, int* bcnt){
    if (blockIdx.x == 1){ bcnt[threadIdx.x] = 0; return; }
    if (threadIdx.x != 0) return;
    int hit = 0;
    for (int i = 0; i < 128; i++){
        int ex = (xu[2 * i] >> 7) & 0xFF;
        if (ex >= 100 && ex <= 140) hit++;
    }
    flags[0] = (hit >= 64) ? 1 : 0;
    int z = 0;
    for (int i = 0; i < 128; i++) if (eiu[2 * i + 1] == 0) z++;
    flags[1] = (z >= 120) ? 1 : 0;
    z = 0;
    for (int i = 0; i < 128; i++) if (bu[49745 + 2 * i] == 0) z++;
    flags[2] = (z >= 120) ? 1 : 0;
}

// ---------------- weight transpose + bf16 prep ----------------
__global__ __launch_bounds__(256) void wtprep_kernel(const void* W0, const void* W1,
                                                     const void* W2, const void* W3,
                                                     unsigned short* wt_all,
                                                     const int* flags){
    int l = blockIdx.x;
    const void* W = (l == 0) ? W0 : (l == 1) ? W1 : (l == 2) ? W2 : W3;
    int K = (l == 0) ? 128 : 96;
    unsigned short* out = wt_all + ((l == 0) ? 0 : (96 * 128 + (l - 1) * 96 * 96));
    int isbf = flags[0];
    int tot = 96 * K;
    for (int i = threadIdx.x; i < tot; i += 256){
        int c = i / K, k = i - c * K;
        out[i] = f2bf(ldflex(W, (long)k * 96 + c, isbf));
    }
}

// ---------------- CSR build: block-aggregated bucket sort ----------------
__global__ __launch_bounds__(256) void bhist_kernel(const int* __restrict__ ei,
                                                    int* __restrict__ bcnt,
                                                    const int* __restrict__ flags){
    __shared__ int h[NBUCK];
    int tid = threadIdx.x;
    h[tid] = 0; __syncthreads();
    int f64 = flags[1];
    long e0 = (long)blockIdx.x * EPB + tid;
    #pragma unroll
    for (int r = 0; r < 16; r++){
        long e = e0 + r * 256;
        if (e < NE){
            int d = ldidx(ei, NE + e, f64);
            atomicAdd(&h[d / BN], 1);
        }
    }
    __syncthreads();
    atomicAdd(&bcnt[tid], h[tid]);
}

__global__ __launch_bounds__(256) void bscan_kernel(const int* __restrict__ bcnt,
                                                    int* __restrict__ bbase,
                                                    int* __restrict__ bcur){
    __shared__ int sd[NBUCK];
    int tid = threadIdx.x;
    int v = bcnt[tid];
    sd[tid] = v; __syncthreads();
    for (int off = 1; off < 256; off <<= 1){
        int x = sd[tid];
        int y = (tid >= off) ? sd[tid - off] : 0;
        __syncthreads();
        sd[tid] = x + y;
        __syncthreads();
    }
    int excl = sd[tid] - v;
    bbase[tid] = excl;
    bcur[tid] = excl;
    if (tid == 255) bbase[256] = excl + v;   // == NE
}

__global__ __launch_bounds__(256) void bscatter_kernel(const int* __restrict__ ei,
                                                       int* __restrict__ bcur,
                                                       int2* __restrict__ ebuf,
                                                       const int* __restrict__ flags){
    __shared__ int h[NBUCK], lofs[NBUCK], gbase[NBUCK], lcur[NBUCK];
    __shared__ int2 lstage[EPB];
    int tid = threadIdx.x;
    int f64 = flags[1];
    h[tid] = 0; __syncthreads();
    int2 ed[16]; int bk[16];
    long e0 = (long)blockIdx.x * EPB + tid;
    #pragma unroll
    for (int r = 0; r < 16; r++){
        long e = e0 + r * 256;
        if (e < NE){
            int s = ldidx(ei, e, f64);
            int d = ldidx(ei, NE + e, f64);
            ed[r] = make_int2(s, d);
            bk[r] = d / BN;
            atomicAdd(&h[bk[r]], 1);
        } else bk[r] = -1;
    }
    __syncthreads();
    int v = h[tid];
    lofs[tid] = v; __syncthreads();
    for (int off = 1; off < 256; off <<= 1){
        int x = lofs[tid];
        int y = (tid >= off) ? lofs[tid - off] : 0;
        __syncthreads();
        lofs[tid] = x + y;
        __syncthreads();
    }
    int excl = lofs[tid] - v;
    lofs[tid] = excl;
    lcur[tid] = excl;
    if (v > 0) gbase[tid] = atomicAdd(&bcur[tid], v);
    __syncthreads();
    #pragma unroll
    for (int r = 0; r < 16; r++){
        if (bk[r] >= 0){
            int p = atomicAdd(&lcur[bk[r]], 1);
            lstage[p] = ed[r];
        }
    }
    __syncthreads();
    long base = (long)blockIdx.x * EPB;
    int cnt = (NE - base < EPB) ? (int)(NE - base) : EPB;
    for (int j = tid; j < cnt; j += 256){
        int2 e = lstage[j];
        int i = e.y / BN;
        ebuf[gbase[i] + j - lofs[i]] = e;
    }
}

// per-bucket: node-level row_ptr + ordered (s,d) csr dump
__global__ __launch_bounds__(256) void place_kernel(const int2* __restrict__ ebuf,
                                                    const int* __restrict__ bbase,
                                                    int* __restrict__ row_ptr,
                                                    int2* __restrict__ csr2){
    __shared__ int nh[BN];
    __shared__ int nofs[256];
    __shared__ int lcur[BN];
    __shared__ int2 stage[SMAX];
    int k = blockIdx.x, tid = threadIdx.x;
    int n0 = k * BN;
    int seg0 = bbase[k], len = bbase[k + 1] - seg0;
    for (int i = tid; i < BN; i += 256) nh[i] = 0;
    __syncthreads();
    for (int j = tid; j < len; j += 256){
        int2 e = ebuf[seg0 + j];
        atomicAdd(&nh[e.y - n0], 1);
    }
    __syncthreads();
    int v = (tid < BN) ? nh[tid] : 0;
    nofs[tid] = v; __syncthreads();
    for (int off = 1; off < 256; off <<= 1){
        int x = nofs[tid];
        int y = (tid >= off) ? nofs[tid - off] : 0;
        __syncthreads();
        nofs[tid] = x + y;
        __syncthreads();
    }
    int excl = nofs[tid] - v;
    if (tid < BN){
        lcur[tid] = excl;
        int node = n0 + tid;
        if (node < NN) row_ptr[node] = seg0 + excl;
    }
    if (k == NBUCK - 1 && tid == 0) row_ptr[NN] = NE;
    __syncthreads();
    if (len <= SMAX){
        for (int j = tid; j < len; j += 256){
            int2 e = ebuf[seg0 + j];
            int p = atomicAdd(&lcur[e.y - n0], 1);
            stage[p] = e;
        }
        __syncthreads();
        for (int j = tid; j < len; j += 256)
            csr2[seg0 + j] = stage[j];
    } else {
        for (int j = tid; j < len; j += 256){
            int2 e = ebuf[seg0 + j];
            int p = atomicAdd(&lcur[e.y - n0], 1);
            csr2[seg0 + p] = e;
        }
    }
}

// ---------------- MFMA GEMM + es/ed/pself + fp8 pack ---------------------
// L1: A is raw x (f32 or bf16 per flag); else A is bf16.
template<int K, int H, bool L1>
__global__ __launch_bounds__(256) void gemm_mfma(const void* __restrict__ Ain,
                                                 const unsigned short* __restrict__ Wt,
                                                 const void* __restrict__ as_,
                                                 const void* __restrict__ ad_,
                                                 unsigned short* __restrict__ hq16,
                                                 float* __restrict__ es,
                                                 float* __restrict__ ed,
                                                 float* __restrict__ pself,
                                                 const int* __restrict__ flags){
    __shared__ union {
        struct { unsigned short xs[64 * 40]; unsigned short wt[96 * 40]; } s;
        float hs[64 * 104];
    } u;
    int tid = threadIdx.x;
    int row0 = blockIdx.x * 64;
    int lane = tid & 63, w = tid >> 6;
    int m = lane & 15, q = lane >> 4;
    int isbf = flags[0];
    float4v acc[6];
    #pragma unroll
    for (int ct = 0; ct < 6; ct++) acc[ct] = (float4v){0.f, 0.f, 0.f, 0.f};

    int sr = tid >> 2, kp = tid & 3;
    int rr = row0 + sr; if (rr >= NN) rr = NN - 1;

    for (int k0 = 0; k0 < K; k0 += 32){
        uint4 av;
        if (L1 && !isbf){
            const float* xf = (const float*)Ain + (size_t)rr * K + k0 + kp * 8;
            float4 f1 = *(const float4*)xf;
            float4 f2 = *(const float4*)(xf + 4);
            av.x = (unsigned)f2bf(f1.x) | ((unsigned)f2bf(f1.y) << 16);
            av.y = (unsigned)f2bf(f1.z) | ((unsigned)f2bf(f1.w) << 16);
            av.z = (unsigned)f2bf(f2.x) | ((unsigned)f2bf(f2.y) << 16);
            av.w = (unsigned)f2bf(f2.z) | ((unsigned)f2bf(f2.w) << 16);
        } else {
            av = *(const uint4*)((const unsigned short*)Ain + (size_t)rr * K + k0 + kp * 8);
        }
        *(uint4*)(u.s.xs + sr * 40 + kp * 8) = av;
        for (int i = tid; i < 96 * 4; i += 256){
            int c = i >> 2, kq = i & 3;
            *(uint4*)(u.s.wt + c * 40 + kq * 8) =
                *(const uint4*)(Wt + (size_t)c * K + k0 + kq * 8);
        }
        __syncthreads();
        short8 a = *(const short8*)(u.s.xs + (w * 16 + m) * 40 + q * 8);
        #pragma unroll
        for (int ct = 0; ct < 6; ct++){
            short8 b = *(const short8*)(u.s.wt + (ct * 16 + m) * 40 + q * 8);
            acc[ct] = __builtin_amdgcn_mfma_f32_16x16x32_bf16(a, b, acc[ct], 0, 0, 0);
        }
        __syncthreads();
    }

    #pragma unroll
    for (int ct = 0; ct < 6; ct++)
        #pragma unroll
        for (int r = 0; r < 4; r++)
            u.hs[(w * 16 + q * 4 + r) * 104 + ct * 16 + m] = acc[ct][r];
    __syncthreads();

    int rl = tid >> 2, part = tid & 3;
    int row = row0 + rl;
    float hv[24];
    #pragma unroll
    for (int jj = 0; jj < 6; jj++)
        *(float4v*)&hv[jj * 4] = *(const float4v*)&u.hs[rl * 104 + part * 24 + jj * 4];

    float pes = 0.f, ped = 0.f;
    #pragma unroll
    for (int i = 0; i < 24; i++){
        int c = part * 24 + i;
        pes += hv[i] * ldflex(as_, c, isbf);
        ped += hv[i] * ldflex(ad_, c, isbf);
    }
    pes += __shfl_xor(pes, 1); ped += __shfl_xor(ped, 1);
    if (H == 1){ pes += __shfl_xor(pes, 2); ped += __shfl_xor(ped, 2); }

    if (row < NN){
        if (part == 0){
            es[(long)row * H] = pes; ed[(long)row * H] = ped;
            pself[(long)row * H] = __expf(lrelu(pes + ped));
        }
        if (H == 2 && part == 2){
            es[(long)row * H + 1] = pes; ed[(long)row * H + 1] = ped;
            pself[(long)row * H + 1] = __expf(lrelu(pes + ped));
        }
        unsigned short wds[12];
        #pragma unroll
        for (int j = 0; j < 12; j++) wds[j] = pk_fp8(hv[2 * j], hv[2 * j + 1]);
        uint2* dst = (uint2*)hq16 + (long)row * 16 + part * 3;
        #pragma unroll
        for (int j2 = 0; j2 < 3; j2++){
            uint2 v;
            v.x = (unsigned)wds[4 * j2] | ((unsigned)wds[4 * j2 + 1] << 16);
            v.y = (unsigned)wds[4 * j2 + 2] | ((unsigned)wds[4 * j2 + 3] << 16);
            dst[j2] = v;
        }
    }
}

// ---------------- per-edge exp scores, packed with src ----------------
template<int H>
__global__ __launch_bounds__(256) void pexp_kernel(const float* __restrict__ es,
                                                   const float* __restrict__ ed,
                                                   const int2* __restrict__ csr2,
                                                   void* __restrict__ edata){
    int i = blockIdx.x * 256 + threadIdx.x;
    if (i >= NE) return;
    int2 e = csr2[i];
    if (H == 1){
        float p = __expf(lrelu(es[e.x] + ed[e.y]));
        ((uint2*)edata)[i] = make_uint2((unsigned)e.x, __float_as_uint(p));
    } else {
        float p0 = __expf(lrelu(es[2 * (long)e.x] + ed[2 * (long)e.y]));
        float p1 = __expf(lrelu(es[2 * (long)e.x + 1] + ed[2 * (long)e.y + 1]));
        ((uint4*)edata)[i] = make_uint4((unsigned)e.x, __float_as_uint(p0),
                                        __float_as_uint(p1), 0u);
    }
}

// ---------------- attention: wave per node, fp8 rows, precomputed p -------
template<int H>
__global__ __launch_bounds__(256) void attn_kernel(const unsigned int* __restrict__ hq,
                                                   const void* __restrict__ edata,
                                                   const float* __restrict__ pself,
                                                   const int* __restrict__ row_ptr,
                                                   const void* __restrict__ bias,
                                                   unsigned int* __restrict__ outb,
                                                   const int* __restrict__ flags){
    int lane = threadIdx.x & 63;
    int d = blockIdx.x * 4 + (threadIdx.x >> 6);
    if (d >= NN) return;
    int isbf = flags[0];
    int beg = row_ptr[d], deg = row_ptr[d + 1] - beg;
    int g = (lane >= 24 && lane < 48) ? 1 : 0;
    int c = lane - g * 24;
    bool head0 = (c < 12);
    int m = lane - 48;

    int s_nxt = 0; float p0_nxt = 0.f, p1_nxt = 0.f;
    if (lane >= 48 && m < deg){
        if (H == 1){
            uint2 e = ((const uint2*)edata)[beg + m];
            s_nxt = (int)e.x; p0_nxt = __uint_as_float(e.y);
        } else {
            uint4 e = ((const uint4*)edata)[beg + m];
            s_nxt = (int)e.x; p0_nxt = __uint_as_float(e.y); p1_nxt = __uint_as_float(e.z);
        }
    }

    float2v acc01 = {0.f, 0.f}, acc23 = {0.f, 0.f};
    float dn0 = 0.f, dn1 = 0.f;
    for (int base = 0; base < deg; base += 16){
        int s_cur = s_nxt; float p0c = p0_nxt, p1c = p1_nxt;
        dn0 += p0c; dn1 += p1c;
        int nb = base + 16;
        s_nxt = 0; p0_nxt = 0.f; p1_nxt = 0.f;
        if (lane >= 48 && nb + m < deg){
            if (H == 1){
                uint2 e = ((const uint2*)edata)[beg + nb + m];
                s_nxt = (int)e.x; p0_nxt = __uint_as_float(e.y);
            } else {
                uint4 e = ((const uint4*)edata)[beg + nb + m];
                s_nxt = (int)e.x; p0_nxt = __uint_as_float(e.y); p1_nxt = __uint_as_float(e.z);
            }
        }
        int cnt = deg - base; if (cnt > 16) cnt = 16;
        if (cnt == 16){
            unsigned int v[8]; float pv[8];
            #pragma unroll
            for (int jj = 0; jj < 8; jj++){
                int idx = 48 + 2 * jj + g;
                int s = __shfl(s_cur, idx);
                float p0 = __shfl(p0c, idx);
                float p;
                if (H == 2){
                    float p1 = __shfl(p1c, idx);
                    p = head0 ? p0 : p1;
                } else p = p0;
                pv[jj] = p;
                v[jj] = (lane < 48) ? hq[(unsigned)s * 32u + (unsigned)c] : 0u;
            }
            #pragma unroll
            for (int jj = 0; jj < 8; jj++){
                float2v lo, hi;
                dec_fp8x4_pk(v[jj], lo, hi);
                float2v p2 = {pv[jj], pv[jj]};
                acc01 += p2 * lo;
                acc23 += p2 * hi;
            }
        } else {
            int njj = (cnt + 1) >> 1;
            for (int jj = 0; jj < njj; jj++){
                int idx = 48 + 2 * jj + g;
                int s = __shfl(s_cur, idx);
                float p0 = __shfl(p0c, idx);
                float p;
                if (H == 2){
                    float p1 = __shfl(p1c, idx);
                    p = head0 ? p0 : p1;
                } else p = p0;
                unsigned int v = (lane < 48) ? hq[(unsigned)s * 32u + (unsigned)c] : 0u;
                float2v lo, hi;
                dec_fp8x4_pk(v, lo, hi);
                float2v p2 = {p, p};
                acc01 += p2 * lo;
                acc23 += p2 * hi;
            }
        }
    }

    for (int off = 1; off < 16; off <<= 1){
        dn0 += __shfl_xor(dn0, off);
        if (H == 2) dn1 += __shfl_xor(dn1, off);
    }
    float dn0_t = rdlane_f(dn0, 48);
    float dn1_t = (H == 2) ? rdlane_f(dn1, 48) : dn0_t;

    float tot[4] = {acc01[0], acc01[1], acc23[0], acc23[1]};
    #pragma unroll
    for (int k = 0; k < 4; k++) tot[k] += __shfl(tot[k], lane + 24);

    if (lane < 24){
        int head = (H == 2) ? (head0 ? 0 : 1) : 0;
        float ps = pself[(long)d * H + head];
        float dn = (head0 ? dn0_t : dn1_t) + ps;
        if (H == 1) dn = dn0_t + ps;
        float2v lo, hi;
        dec_fp8x4_pk(hq[(unsigned)d * 32u + (unsigned)c], lo, hi);
        float o0 = fmaxf((tot[0] + ps * lo[0]) / dn + ldflex(bias, 4 * c + 0, isbf), 0.f);
        float o1 = fmaxf((tot[1] + ps * lo[1]) / dn + ldflex(bias, 4 * c + 1, isbf), 0.f);
        float o2 = fmaxf((tot[2] + ps * hi[0]) / dn + ldflex(bias, 4 * c + 2, isbf), 0.f);
        float o3 = fmaxf((tot[3] + ps * hi[1]) / dn + ldflex(bias, 4 * c + 3, isbf), 0.f);
        uint2 vv;
        vv.x = (unsigned)f2bf(o0) | ((unsigned)f2bf(o1) << 16);
        vv.y = (unsigned)f2bf(o2) | ((unsigned)f2bf(o3) << 16);
        ((uint2*)outb)[(long)d * 24 + c] = vv;
    }
}

// ---------------- fused mean-pool + classifier (one block per graph) ------
__global__ __launch_bounds__(256) void poolfinal_kernel(const unsigned int* __restrict__ bufb,
                                                        const int* __restrict__ batch,
                                                        const void* __restrict__ Wc,
                                                        const void* __restrict__ bc,
                                                        void* __restrict__ outp,
                                                        const int* __restrict__ flags){
    __shared__ int slo, shi;
    __shared__ float part[4][96];
    int gg = blockIdx.x;
    int tid = threadIdx.x;
    int isbf = flags[0], f64 = flags[2];
    if (tid == 0){
        int lo = 0, hi = NN;
        while (lo < hi){ int mid = (lo + hi) >> 1; if (ldidx(batch, mid, f64) < gg) lo = mid + 1; else hi = mid; }
        slo = lo;
        hi = NN;
        while (lo < hi){ int mid = (lo + hi) >> 1; if (ldidx(batch, mid, f64) < gg + 1) lo = mid + 1; else hi = mid; }
        shi = lo;
    }
    __syncthreads();
    int lane = tid & 63, w = tid >> 6;
    float a0 = 0.f, a1 = 0.f;
    if (lane < 48){
        for (int nd = slo + w; nd < shi; nd += 4){
            unsigned v = bufb[(long)nd * 48 + lane];
            a0 += bf2f((unsigned short)v);
            a1 += bf2f((unsigned short)(v >> 16));
        }
        part[w][2 * lane] = a0;
        part[w][2 * lane + 1] = a1;
    }
    __syncthreads();
    if (tid < 96){
        float s = part[0][tid] + part[1][tid] + part[2][tid] + part[3][tid];
        int cnt = shi - slo;
        float mean = s / fmaxf((float)cnt, 1.f);
        part[0][tid] = mean * ldflex(Wc, tid, isbf);
    }
    __syncthreads();
    if (tid == 0){
        float acc = 0.f;
        for (int i = 0; i < 96; i++) acc += part[0][i];
        acc += ldflex(bc, 0, isbf);
        float sg = 1.f / (1.f + __expf(-acc));
        if (isbf) ((unsigned short*)outp)[gg] = f2bf(sg);
        else      ((float*)outp)[gg] = sg;
    }
}

extern "C" void kernel_launch(void* const* d_in, const int* in_sizes, int n_in,
                              void* d_out, int out_size, void* d_ws, size_t ws_size,
                              hipStream_t stream){
    const void* x     = d_in[0];
    const int* ei     = (const int*)d_in[1];
    const int* batch  = (const int*)d_in[3];
    const void* W[4]  = {d_in[4],  d_in[8],  d_in[12], d_in[16]};
    const void* AS[4] = {d_in[5],  d_in[9],  d_in[13], d_in[17]};
    const void* AD[4] = {d_in[6],  d_in[10], d_in[14], d_in[18]};
    const void* B[4]  = {d_in[7],  d_in[11], d_in[15], d_in[19]};
    const void* Wc    = d_in[20];
    const void* bc    = d_in[21];

    char* p = (char*)d_ws;
    auto alloc = [&](size_t bytes) -> void* {
        void* r = (void*)p;
        p += (bytes + 255) & ~(size_t)255;
        return r;
    };
    int* flags     = (int*)alloc(16);
    unsigned int* hq = (unsigned int*)alloc((size_t)NN * 128);        // fp8 rows, 128B stride
    unsigned int* buf1b = (unsigned int*)alloc((size_t)NN * 96 * 2);  // bf16 attn out
    void* edata    = alloc((size_t)NE * 16);                          // per-edge packed scores
    unsigned short* wt_all = (unsigned short*)alloc((size_t)(96 * 128 + 3 * 96 * 96) * 2);
    float* es      = (float*)alloc((size_t)NN * 2 * 4);
    float* ed      = (float*)alloc((size_t)NN * 2 * 4);
    float* pself   = (float*)alloc((size_t)NN * 2 * 4);
    int* row_ptr   = (int*)alloc((size_t)(NN + 1) * 4);
    int2* csr2     = (int2*)alloc((size_t)NE * 8);
    int2* ebuf     = (int2*)alloc((size_t)NE * 8);
    int* bcnt      = (int*)alloc((size_t)NBUCK * 4);
    int* bbase     = (int*)alloc((size_t)(NBUCK + 1) * 4);
    int* bcur      = (int*)alloc((size_t)NBUCK * 4);

    detect_kernel<<<2, 256, 0, stream>>>((const unsigned short*)x, (const unsigned int*)ei,
                                         (const unsigned int*)batch, flags, bcnt);
    wtprep_kernel<<<4, 256, 0, stream>>>(W[0], W[1], W[2], W[3], wt_all, flags);

    // CSR build: LDS-aggregated bucket sort
    bhist_kernel<<<HB, 256, 0, stream>>>(ei, bcnt, flags);
    bscan_kernel<<<1, 256, 0, stream>>>(bcnt, bbase, bcur);
    bscatter_kernel<<<HB, 256, 0, stream>>>(ei, bcur, ebuf, flags);
    place_kernel<<<NBUCK, 256, 0, stream>>>(ebuf, bbase, row_ptr, csr2);

    const int GB = (NN + 63) / 64;        // 782
    const int AB = (NN + 3) / 4;          // 12500
    const int EB = (NE + 255) / 256;      // 3125
    unsigned short* wt1 = wt_all;
    unsigned short* wt2 = wt_all + 96 * 128;
    unsigned short* wt3 = wt2 + 96 * 96;
    unsigned short* wt4 = wt3 + 96 * 96;

    // layer 1 (H=2, K=128): reads x directly (f32 or bf16 per flag)
    gemm_mfma<128, 2, true><<<GB, 256, 0, stream>>>(x, wt1, AS[0], AD[0],
                                                    (unsigned short*)hq, es, ed, pself, flags);
    pexp_kernel<2><<<EB, 256, 0, stream>>>(es, ed, csr2, edata);
    attn_kernel<2><<<AB, 256, 0, stream>>>(hq, edata, pself, row_ptr, B[0], buf1b, flags);
    // layers 2..4 (H=1, K=96)
    unsigned short* wts[3] = {wt2, wt3, wt4};
    for (int l = 1; l < 4; l++){
        gemm_mfma<96, 1, false><<<GB, 256, 0, stream>>>(buf1b, wts[l - 1], AS[l], AD[l],
                                                        (unsigned short*)hq, es, ed, pself, flags);
        pexp_kernel<1><<<EB, 256, 0, stream>>>(es, ed, csr2, edata);
        attn_kernel<1><<<AB, 256, 0, stream>>>(hq, edata, pself, row_ptr, B[l], buf1b, flags);
    }

    poolfinal_kernel<<<NG, 256, 0, stream>>>(buf1b, batch, Wc, bc, d_out, flags);
}

// Round 13
// 421.559 us; speedup vs baseline: 1.0833x; 1.0833x over previous
//
#include <hip/hip_runtime.h>
#include <hip/hip_bf16.h>

#define NN 50000
#define NE 800000
#define NG 64
#define NBUCK 256
#define BN 196        // nodes per bucket; 256*196 = 50176 >= NN
#define EPB 4096      // edges per binning block
#define HB 196        // ceil(NE/EPB)
#define SMAX 4200     // per-bucket segment capacity (mean 3136, sigma 56)

typedef __attribute__((ext_vector_type(8))) short short8;
typedef __attribute__((ext_vector_type(4))) float float4v;
typedef __attribute__((ext_vector_type(2))) float float2v;

__device__ __forceinline__ float bf2f(unsigned short u){
    unsigned v = ((unsigned)u) << 16; float f; __builtin_memcpy(&f, &v, 4); return f;
}
__device__ __forceinline__ unsigned short f2bf(float f){
    unsigned u; __builtin_memcpy(&u, &f, 4);
    u = (u + 0x7fffu + ((u >> 16) & 1u)) >> 16;
    return (unsigned short)u;
}
__device__ __forceinline__ float lrelu(float v){ return v > 0.f ? v : 0.2f * v; }

__device__ __forceinline__ float ldflex(const void* p, long i, int isbf){
    if (isbf) return bf2f(((const unsigned short*)p)[i]);
    return ((const float*)p)[i];
}
__device__ __forceinline__ int ldidx(const int* p, long i, int is64){
    return p[is64 ? (i << 1) : i];
}

// ---- fp8 e4m3fn (OCP) pack/unpack, HW cvt when available ----
__device__ __forceinline__ unsigned int enc_fp8_1(float f){
    unsigned u; __builtin_memcpy(&u, &f, 4);
    unsigned s = (u >> 24) & 0x80u;
    float a = fabsf(f); a = fminf(a, 448.f);
    float x = a * 0x1p-120f;
    unsigned xu; __builtin_memcpy(&xu, &x, 4);
    unsigned r = (xu + 0x7FFFFu + ((xu >> 20) & 1u)) >> 20;
    if (r > 0x7Eu) r = 0x7Eu;
    return s | r;
}
__device__ __forceinline__ unsigned short pk_fp8(float a, float b){
#if __has_builtin(__builtin_amdgcn_cvt_pk_fp8_f32)
    int r = __builtin_amdgcn_cvt_pk_fp8_f32(a, b, 0, false);
    return (unsigned short)(r & 0xFFFF);
#else
    return (unsigned short)(enc_fp8_1(a) | (enc_fp8_1(b) << 8));
#endif
}
__device__ __forceinline__ float dec_fp8_manual(unsigned int byte){
    unsigned bits = ((byte & 0x80u) << 24) | ((byte & 0x7Fu) << 20);
    float f; __builtin_memcpy(&f, &bits, 4);
    return f * 0x1p120f;
}
__device__ __forceinline__ void dec_fp8x4_pk(unsigned int v, float2v& lo, float2v& hi){
#if __has_builtin(__builtin_amdgcn_cvt_pk_f32_fp8)
    lo = __builtin_amdgcn_cvt_pk_f32_fp8((int)v, false);
    hi = __builtin_amdgcn_cvt_pk_f32_fp8((int)v, true);
#else
    lo[0] = dec_fp8_manual(v & 0xFF);
    lo[1] = dec_fp8_manual((v >> 8) & 0xFF);
    hi[0] = dec_fp8_manual((v >> 16) & 0xFF);
    hi[1] = dec_fp8_manual((v >> 24) & 0xFF);
#endif
}

__device__ __forceinline__ float rdlane_f(float v, int l){
    int i; __builtin_memcpy(&i, &v, 4);
    int r = __builtin_amdgcn_readlane(i, l);
    float f; __builtin_memcpy(&f, &r, 4);
    return f;
}

// ---------------- runtime dtype detection + buffer zeroing ----------------
__global__ void detect_kernel(const unsigned short* xu, const unsigned int* eiu,
                              const unsigned int* bu, int* flags, int* bcnt,
                              float* pooled, int* gcnt){
    if (blockIdx.x == 1){
        int tid = threadIdx.x;
        bcnt[tid] = 0;
        for (int i = tid; i < NG * 96; i += 256) pooled[i] = 0.f;
        if (tid < NG) gcnt[tid] = 0;
        return;
    }
    if (threadIdx.x != 0) return;
    int hit = 0;
    for (int i = 0; i < 128; i++){
        int ex = (xu[2 * i] >> 7) & 0xFF;
        if (ex >= 100 && ex <= 140) hit++;
    }
    flags[0] = (hit >= 64) ? 1 : 0;
    int z = 0;
    for (int i = 0; i < 128; i++) if (eiu[2 * i + 1] == 0) z++;
    flags[1] = (z >= 120) ? 1 : 0;
    z = 0;
    for (int i = 0; i < 128; i++) if (bu[49745 + 2 * i] == 0) z++;
    flags[2] = (z >= 120) ? 1 : 0;
}

// ---------------- weight transpose + bf16 prep ----------------
__global__ __launch_bounds__(256) void wtprep_kernel(const void* W0, const void* W1,
                                                     const void* W2, const void* W3,
                                                     unsigned short* wt_all,
                                                     const int* flags){
    int l = blockIdx.x;
    const void* W = (l == 0) ? W0 : (l == 1) ? W1 : (l == 2) ? W2 : W3;
    int K = (l == 0) ? 128 : 96;
    unsigned short* out = wt_all + ((l == 0) ? 0 : (96 * 128 + (l - 1) * 96 * 96));
    int isbf = flags[0];
    int tot = 96 * K;
    for (int i = threadIdx.x; i < tot; i += 256){
        int c = i / K, k = i - c * K;
        out[i] = f2bf(ldflex(W, (long)k * 96 + c, isbf));
    }
}

// ---------------- CSR build: block-aggregated bucket sort ----------------
__global__ __launch_bounds__(256) void bhist_kernel(const int* __restrict__ ei,
                                                    int* __restrict__ bcnt,
                                                    const int* __restrict__ flags){
    __shared__ int h[NBUCK];
    int tid = threadIdx.x;
    h[tid] = 0; __syncthreads();
    int f64 = flags[1];
    long e0 = (long)blockIdx.x * EPB + tid;
    #pragma unroll
    for (int r = 0; r < 16; r++){
        long e = e0 + r * 256;
        if (e < NE){
            int d = ldidx(ei, NE + e, f64);
            atomicAdd(&h[d / BN], 1);
        }
    }
    __syncthreads();
    atomicAdd(&bcnt[tid], h[tid]);
}

__global__ __launch_bounds__(256) void bscan_kernel(const int* __restrict__ bcnt,
                                                    int* __restrict__ bbase,
                                                    int* __restrict__ bcur){
    __shared__ int sd[NBUCK];
    int tid = threadIdx.x;
    int v = bcnt[tid];
    sd[tid] = v; __syncthreads();
    for (int off = 1; off < 256; off <<= 1){
        int x = sd[tid];
        int y = (tid >= off) ? sd[tid - off] : 0;
        __syncthreads();
        sd[tid] = x + y;
        __syncthreads();
    }
    int excl = sd[tid] - v;
    bbase[tid] = excl;
    bcur[tid] = excl;
    if (tid == 255) bbase[256] = excl + v;   // == NE
}

__global__ __launch_bounds__(256) void bscatter_kernel(const int* __restrict__ ei,
                                                       int* __restrict__ bcur,
                                                       int2* __restrict__ ebuf,
                                                       const int* __restrict__ flags){
    __shared__ int h[NBUCK], lofs[NBUCK], gbase[NBUCK], lcur[NBUCK];
    __shared__ int2 lstage[EPB];
    int tid = threadIdx.x;
    int f64 = flags[1];
    h[tid] = 0; __syncthreads();
    int2 ed[16]; int bk[16];
    long e0 = (long)blockIdx.x * EPB + tid;
    #pragma unroll
    for (int r = 0; r < 16; r++){
        long e = e0 + r * 256;
        if (e < NE){
            int s = ldidx(ei, e, f64);
            int d = ldidx(ei, NE + e, f64);
            ed[r] = make_int2(s, d);
            bk[r] = d / BN;
            atomicAdd(&h[bk[r]], 1);
        } else bk[r] = -1;
    }
    __syncthreads();
    int v = h[tid];
    lofs[tid] = v; __syncthreads();
    for (int off = 1; off < 256; off <<= 1){
        int x = lofs[tid];
        int y = (tid >= off) ? lofs[tid - off] : 0;
        __syncthreads();
        lofs[tid] = x + y;
        __syncthreads();
    }
    int excl = lofs[tid] - v;
    lofs[tid] = excl;
    lcur[tid] = excl;
    if (v > 0) gbase[tid] = atomicAdd(&bcur[tid], v);
    __syncthreads();
    #pragma unroll
    for (int r = 0; r < 16; r++){
        if (bk[r] >= 0){
            int p = atomicAdd(&lcur[bk[r]], 1);
            lstage[p] = ed[r];
        }
    }
    __syncthreads();
    long base = (long)blockIdx.x * EPB;
    int cnt = (NE - base < EPB) ? (int)(NE - base) : EPB;
    for (int j = tid; j < cnt; j += 256){
        int2 e = lstage[j];
        int i = e.y / BN;
        ebuf[gbase[i] + j - lofs[i]] = e;
    }
}

// per-bucket: node-level row_ptr + ordered (s,d) csr dump
__global__ __launch_bounds__(256) void place_kernel(const int2* __restrict__ ebuf,
                                                    const int* __restrict__ bbase,
                                                    int* __restrict__ row_ptr,
                                                    int2* __restrict__ csr2){
    __shared__ int nh[BN];
    __shared__ int nofs[256];
    __shared__ int lcur[BN];
    __shared__ int2 stage[SMAX];
    int k = blockIdx.x, tid = threadIdx.x;
    int n0 = k * BN;
    int seg0 = bbase[k], len = bbase[k + 1] - seg0;
    for (int i = tid; i < BN; i += 256) nh[i] = 0;
    __syncthreads();
    for (int j = tid; j < len; j += 256){
        int2 e = ebuf[seg0 + j];
        atomicAdd(&nh[e.y - n0], 1);
    }
    __syncthreads();
    int v = (tid < BN) ? nh[tid] : 0;
    nofs[tid] = v; __syncthreads();
    for (int off = 1; off < 256; off <<= 1){
        int x = nofs[tid];
        int y = (tid >= off) ? nofs[tid - off] : 0;
        __syncthreads();
        nofs[tid] = x + y;
        __syncthreads();
    }
    int excl = nofs[tid] - v;
    if (tid < BN){
        lcur[tid] = excl;
        int node = n0 + tid;
        if (node < NN) row_ptr[node] = seg0 + excl;
    }
    if (k == NBUCK - 1 && tid == 0) row_ptr[NN] = NE;
    __syncthreads();
    if (len <= SMAX){
        for (int j = tid; j < len; j += 256){
            int2 e = ebuf[seg0 + j];
            int p = atomicAdd(&lcur[e.y - n0], 1);
            stage[p] = e;
        }
        __syncthreads();
        for (int j = tid; j < len; j += 256)
            csr2[seg0 + j] = stage[j];
    } else {
        for (int j = tid; j < len; j += 256){
            int2 e = ebuf[seg0 + j];
            int p = atomicAdd(&lcur[e.y - n0], 1);
            csr2[seg0 + p] = e;
        }
    }
}

// ---------------- MFMA GEMM + es/ed/pself + fp8 pack ---------------------
// L1: A is raw x (f32 or bf16 per flag); else A is bf16.
template<int K, int H, bool L1>
__global__ __launch_bounds__(256) void gemm_mfma(const void* __restrict__ Ain,
                                                 const unsigned short* __restrict__ Wt,
                                                 const void* __restrict__ as_,
                                                 const void* __restrict__ ad_,
                                                 unsigned short* __restrict__ hq16,
                                                 float* __restrict__ es,
                                                 float* __restrict__ ed,
                                                 float* __restrict__ pself,
                                                 const int* __restrict__ flags){
    __shared__ union {
        struct { unsigned short xs[64 * 40]; unsigned short wt[96 * 40]; } s;
        float hs[64 * 104];
    } u;
    int tid = threadIdx.x;
    int row0 = blockIdx.x * 64;
    int lane = tid & 63, w = tid >> 6;
    int m = lane & 15, q = lane >> 4;
    int isbf = flags[0];
    float4v acc[6];
    #pragma unroll
    for (int ct = 0; ct < 6; ct++) acc[ct] = (float4v){0.f, 0.f, 0.f, 0.f};

    int sr = tid >> 2, kp = tid & 3;
    int rr = row0 + sr; if (rr >= NN) rr = NN - 1;

    for (int k0 = 0; k0 < K; k0 += 32){
        uint4 av;
        if (L1 && !isbf){
            const float* xf = (const float*)Ain + (size_t)rr * K + k0 + kp * 8;
            float4 f1 = *(const float4*)xf;
            float4 f2 = *(const float4*)(xf + 4);
            av.x = (unsigned)f2bf(f1.x) | ((unsigned)f2bf(f1.y) << 16);
            av.y = (unsigned)f2bf(f1.z) | ((unsigned)f2bf(f1.w) << 16);
            av.z = (unsigned)f2bf(f2.x) | ((unsigned)f2bf(f2.y) << 16);
            av.w = (unsigned)f2bf(f2.z) | ((unsigned)f2bf(f2.w) << 16);
        } else {
            av = *(const uint4*)((const unsigned short*)Ain + (size_t)rr * K + k0 + kp * 8);
        }
        *(uint4*)(u.s.xs + sr * 40 + kp * 8) = av;
        for (int i = tid; i < 96 * 4; i += 256){
            int c = i >> 2, kq = i & 3;
            *(uint4*)(u.s.wt + c * 40 + kq * 8) =
                *(const uint4*)(Wt + (size_t)c * K + k0 + kq * 8);
        }
        __syncthreads();
        short8 a = *(const short8*)(u.s.xs + (w * 16 + m) * 40 + q * 8);
        #pragma unroll
        for (int ct = 0; ct < 6; ct++){
            short8 b = *(const short8*)(u.s.wt + (ct * 16 + m) * 40 + q * 8);
            acc[ct] = __builtin_amdgcn_mfma_f32_16x16x32_bf16(a, b, acc[ct], 0, 0, 0);
        }
        __syncthreads();
    }

    #pragma unroll
    for (int ct = 0; ct < 6; ct++)
        #pragma unroll
        for (int r = 0; r < 4; r++)
            u.hs[(w * 16 + q * 4 + r) * 104 + ct * 16 + m] = acc[ct][r];
    __syncthreads();

    int rl = tid >> 2, part = tid & 3;
    int row = row0 + rl;
    float hv[24];
    #pragma unroll
    for (int jj = 0; jj < 6; jj++)
        *(float4v*)&hv[jj * 4] = *(const float4v*)&u.hs[rl * 104 + part * 24 + jj * 4];

    float pes = 0.f, ped = 0.f;
    #pragma unroll
    for (int i = 0; i < 24; i++){
        int c = part * 24 + i;
        pes += hv[i] * ldflex(as_, c, isbf);
        ped += hv[i] * ldflex(ad_, c, isbf);
    }
    pes += __shfl_xor(pes, 1); ped += __shfl_xor(ped, 1);
    if (H == 1){ pes += __shfl_xor(pes, 2); ped += __shfl_xor(ped, 2); }

    if (row < NN){
        if (part == 0){
            es[(long)row * H] = pes; ed[(long)row * H] = ped;
            pself[(long)row * H] = __expf(lrelu(pes + ped));
        }
        if (H == 2 && part == 2){
            es[(long)row * H + 1] = pes; ed[(long)row * H + 1] = ped;
            pself[(long)row * H + 1] = __expf(lrelu(pes + ped));
        }
        unsigned short wds[12];
        #pragma unroll
        for (int j = 0; j < 12; j++) wds[j] = pk_fp8(hv[2 * j], hv[2 * j + 1]);
        uint2* dst = (uint2*)hq16 + (long)row * 16 + part * 3;
        #pragma unroll
        for (int j2 = 0; j2 < 3; j2++){
            uint2 v;
            v.x = (unsigned)wds[4 * j2] | ((unsigned)wds[4 * j2 + 1] << 16);
            v.y = (unsigned)wds[4 * j2 + 2] | ((unsigned)wds[4 * j2 + 3] << 16);
            dst[j2] = v;
        }
    }
}

// ---------------- per-edge exp scores, packed with src ----------------
template<int H>
__global__ __launch_bounds__(256) void pexp_kernel(const float* __restrict__ es,
                                                   const float* __restrict__ ed,
                                                   const int2* __restrict__ csr2,
                                                   void* __restrict__ edata){
    int i = blockIdx.x * 256 + threadIdx.x;
    if (i >= NE) return;
    int2 e = csr2[i];
    if (H == 1){
        float p = __expf(lrelu(es[e.x] + ed[e.y]));
        ((uint2*)edata)[i] = make_uint2((unsigned)e.x, __float_as_uint(p));
    } else {
        float p0 = __expf(lrelu(es[2 * (long)e.x] + ed[2 * (long)e.y]));
        float p1 = __expf(lrelu(es[2 * (long)e.x + 1] + ed[2 * (long)e.y + 1]));
        ((uint4*)edata)[i] = make_uint4((unsigned)e.x, __float_as_uint(p0),
                                        __float_as_uint(p1), 0u);
    }
}

// ---------------- attention: wave per node, fp8 rows, precomputed p -------
template<int H>
__global__ __launch_bounds__(256) void attn_kernel(const unsigned int* __restrict__ hq,
                                                   const void* __restrict__ edata,
                                                   const float* __restrict__ pself,
                                                   const int* __restrict__ row_ptr,
                                                   const void* __restrict__ bias,
                                                   unsigned int* __restrict__ outb,
                                                   const int* __restrict__ flags){
    int lane = threadIdx.x & 63;
    int d = blockIdx.x * 4 + (threadIdx.x >> 6);
    if (d >= NN) return;
    int isbf = flags[0];
    int beg = row_ptr[d], deg = row_ptr[d + 1] - beg;
    int g = (lane >= 24 && lane < 48) ? 1 : 0;
    int c = lane - g * 24;
    bool head0 = (c < 12);
    int m = lane - 48;

    int s_nxt = 0; float p0_nxt = 0.f, p1_nxt = 0.f;
    if (lane >= 48 && m < deg){
        if (H == 1){
            uint2 e = ((const uint2*)edata)[beg + m];
            s_nxt = (int)e.x; p0_nxt = __uint_as_float(e.y);
        } else {
            uint4 e = ((const uint4*)edata)[beg + m];
            s_nxt = (int)e.x; p0_nxt = __uint_as_float(e.y); p1_nxt = __uint_as_float(e.z);
        }
    }

    float2v acc01 = {0.f, 0.f}, acc23 = {0.f, 0.f};
    float dn0 = 0.f, dn1 = 0.f;
    for (int base = 0; base < deg; base += 16){
        int s_cur = s_nxt; float p0c = p0_nxt, p1c = p1_nxt;
        dn0 += p0c; dn1 += p1c;
        int nb = base + 16;
        s_nxt = 0; p0_nxt = 0.f; p1_nxt = 0.f;
        if (lane >= 48 && nb + m < deg){
            if (H == 1){
                uint2 e = ((const uint2*)edata)[beg + nb + m];
                s_nxt = (int)e.x; p0_nxt = __uint_as_float(e.y);
            } else {
                uint4 e = ((const uint4*)edata)[beg + nb + m];
                s_nxt = (int)e.x; p0_nxt = __uint_as_float(e.y); p1_nxt = __uint_as_float(e.z);
            }
        }
        int cnt = deg - base; if (cnt > 16) cnt = 16;
        if (cnt == 16){
            unsigned int v[8]; float pv[8];
            #pragma unroll
            for (int jj = 0; jj < 8; jj++){
                int idx = 48 + 2 * jj + g;
                int s = __shfl(s_cur, idx);
                float p0 = __shfl(p0c, idx);
                float p;
                if (H == 2){
                    float p1 = __shfl(p1c, idx);
                    p = head0 ? p0 : p1;
                } else p = p0;
                pv[jj] = p;
                v[jj] = (lane < 48) ? hq[(unsigned)s * 32u + (unsigned)c] : 0u;
            }
            #pragma unroll
            for (int jj = 0; jj < 8; jj++){
                float2v lo, hi;
                dec_fp8x4_pk(v[jj], lo, hi);
                float2v p2 = {pv[jj], pv[jj]};
                acc01 += p2 * lo;
                acc23 += p2 * hi;
            }
        } else {
            int njj = (cnt + 1) >> 1;
            for (int jj = 0; jj < njj; jj++){
                int idx = 48 + 2 * jj + g;
                int s = __shfl(s_cur, idx);
                float p0 = __shfl(p0c, idx);
                float p;
                if (H == 2){
                    float p1 = __shfl(p1c, idx);
                    p = head0 ? p0 : p1;
                } else p = p0;
                unsigned int v = (lane < 48) ? hq[(unsigned)s * 32u + (unsigned)c] : 0u;
                float2v lo, hi;
                dec_fp8x4_pk(v, lo, hi);
                float2v p2 = {p, p};
                acc01 += p2 * lo;
                acc23 += p2 * hi;
            }
        }
    }

    for (int off = 1; off < 16; off <<= 1){
        dn0 += __shfl_xor(dn0, off);
        if (H == 2) dn1 += __shfl_xor(dn1, off);
    }
    float dn0_t = rdlane_f(dn0, 48);
    float dn1_t = (H == 2) ? rdlane_f(dn1, 48) : dn0_t;

    float tot[4] = {acc01[0], acc01[1], acc23[0], acc23[1]};
    #pragma unroll
    for (int k = 0; k < 4; k++) tot[k] += __shfl(tot[k], lane + 24);

    if (lane < 24){
        int head = (H == 2) ? (head0 ? 0 : 1) : 0;
        float ps = pself[(long)d * H + head];
        float dn = (head0 ? dn0_t : dn1_t) + ps;
        if (H == 1) dn = dn0_t + ps;
        float2v lo, hi;
        dec_fp8x4_pk(hq[(unsigned)d * 32u + (unsigned)c], lo, hi);
        float o0 = fmaxf((tot[0] + ps * lo[0]) / dn + ldflex(bias, 4 * c + 0, isbf), 0.f);
        float o1 = fmaxf((tot[1] + ps * lo[1]) / dn + ldflex(bias, 4 * c + 1, isbf), 0.f);
        float o2 = fmaxf((tot[2] + ps * hi[0]) / dn + ldflex(bias, 4 * c + 2, isbf), 0.f);
        float o3 = fmaxf((tot[3] + ps * hi[1]) / dn + ldflex(bias, 4 * c + 3, isbf), 0.f);
        uint2 vv;
        vv.x = (unsigned)f2bf(o0) | ((unsigned)f2bf(o1) << 16);
        vv.y = (unsigned)f2bf(o2) | ((unsigned)f2bf(o3) << 16);
        ((uint2*)outb)[(long)d * 24 + c] = vv;
    }
}

// ---------------- pooling (bf16 input rows, 32 nodes/block) ----------------
__global__ __launch_bounds__(64) void pool_kernel(const unsigned int* __restrict__ bufb,
                                                  const int* __restrict__ batch,
                                                  float* __restrict__ pooled,
                                                  int* __restrict__ gcnt,
                                                  const int* __restrict__ flags){
    int f64 = flags[2];
    int n0 = blockIdx.x * 32;
    if (n0 >= NN) return;
    int n1 = n0 + 32; if (n1 > NN) n1 = NN;
    int lane = threadIdx.x;
    if (lane < 48){
        float a0 = 0.f, a1 = 0.f;
        int curg = ldidx(batch, n0, f64);
        for (int nd = n0; nd < n1; nd++){
            int g = ldidx(batch, nd, f64);
            if (g != curg){
                atomicAdd(&pooled[curg * 96 + 2 * lane], a0);
                atomicAdd(&pooled[curg * 96 + 2 * lane + 1], a1);
                a0 = a1 = 0.f; curg = g;
            }
            unsigned v = bufb[(long)nd * 48 + lane];
            a0 += bf2f((unsigned short)v);
            a1 += bf2f((unsigned short)(v >> 16));
        }
        atomicAdd(&pooled[curg * 96 + 2 * lane], a0);
        atomicAdd(&pooled[curg * 96 + 2 * lane + 1], a1);
    } else if (lane == 48){
        int cnt = 0;
        int curg = ldidx(batch, n0, f64);
        for (int nd = n0; nd < n1; nd++){
            int g = ldidx(batch, nd, f64);
            if (g != curg){
                atomicAdd(&gcnt[curg], cnt);
                cnt = 0; curg = g;
            }
            cnt++;
        }
        atomicAdd(&gcnt[curg], cnt);
    }
}

__global__ void final_kernel(const float* __restrict__ pooled, const int* __restrict__ gcnt,
                             const void* __restrict__ Wc, const void* __restrict__ bc,
                             void* __restrict__ outp, const int* __restrict__ flags){
    int isbf = flags[0];
    int g = threadIdx.x;
    if (g >= NG) return;
    float cnt = (float)gcnt[g];
    if (cnt < 1.f) cnt = 1.f;
    float acc = 0.f;
    for (int c = 0; c < 96; c++)
        acc += (pooled[g * 96 + c] / cnt) * ldflex(Wc, c, isbf);
    acc += ldflex(bc, 0, isbf);
    float sg = 1.f / (1.f + __expf(-acc));
    if (isbf) ((unsigned short*)outp)[g] = f2bf(sg);
    else      ((float*)outp)[g] = sg;
}

extern "C" void kernel_launch(void* const* d_in, const int* in_sizes, int n_in,
                              void* d_out, int out_size, void* d_ws, size_t ws_size,
                              hipStream_t stream){
    const void* x     = d_in[0];
    const int* ei     = (const int*)d_in[1];
    const int* batch  = (const int*)d_in[3];
    const void* W[4]  = {d_in[4],  d_in[8],  d_in[12], d_in[16]};
    const void* AS[4] = {d_in[5],  d_in[9],  d_in[13], d_in[17]};
    const void* AD[4] = {d_in[6],  d_in[10], d_in[14], d_in[18]};
    const void* B[4]  = {d_in[7],  d_in[11], d_in[15], d_in[19]};
    const void* Wc    = d_in[20];
    const void* bc    = d_in[21];

    char* p = (char*)d_ws;
    auto alloc = [&](size_t bytes) -> void* {
        void* r = (void*)p;
        p += (bytes + 255) & ~(size_t)255;
        return r;
    };
    int* flags     = (int*)alloc(16);
    unsigned int* hq = (unsigned int*)alloc((size_t)NN * 128);        // fp8 rows, 128B stride
    unsigned int* buf1b = (unsigned int*)alloc((size_t)NN * 96 * 2);  // bf16 attn out
    void* edata    = alloc((size_t)NE * 16);                          // per-edge packed scores
    unsigned short* wt_all = (unsigned short*)alloc((size_t)(96 * 128 + 3 * 96 * 96) * 2);
    float* es      = (float*)alloc((size_t)NN * 2 * 4);
    float* ed      = (float*)alloc((size_t)NN * 2 * 4);
    float* pself   = (float*)alloc((size_t)NN * 2 * 4);
    int* row_ptr   = (int*)alloc((size_t)(NN + 1) * 4);
    int2* csr2     = (int2*)alloc((size_t)NE * 8);
    int2* ebuf     = (int2*)alloc((size_t)NE * 8);
    int* bcnt      = (int*)alloc((size_t)NBUCK * 4);
    int* bbase     = (int*)alloc((size_t)(NBUCK + 1) * 4);
    int* bcur      = (int*)alloc((size_t)NBUCK * 4);
    float* pooled  = (float*)alloc((size_t)NG * 96 * 4);
    int* gcnt      = (int*)alloc((size_t)NG * 4);

    detect_kernel<<<2, 256, 0, stream>>>((const unsigned short*)x, (const unsigned int*)ei,
                                         (const unsigned int*)batch, flags, bcnt, pooled, gcnt);
    wtprep_kernel<<<4, 256, 0, stream>>>(W[0], W[1], W[2], W[3], wt_all, flags);

    // CSR build: LDS-aggregated bucket sort
    bhist_kernel<<<HB, 256, 0, stream>>>(ei, bcnt, flags);
    bscan_kernel<<<1, 256, 0, stream>>>(bcnt, bbase, bcur);
    bscatter_kernel<<<HB, 256, 0, stream>>>(ei, bcur, ebuf, flags);
    place_kernel<<<NBUCK, 256, 0, stream>>>(ebuf, bbase, row_ptr, csr2);

    const int GB = (NN + 63) / 64;        // 782
    const int AB = (NN + 3) / 4;          // 12500
    const int EB = (NE + 255) / 256;      // 3125
    unsigned short* wt1 = wt_all;
    unsigned short* wt2 = wt_all + 96 * 128;
    unsigned short* wt3 = wt2 + 96 * 96;
    unsigned short* wt4 = wt3 + 96 * 96;

    // layer 1 (H=2, K=128): reads x directly (f32 or bf16 per flag)
    gemm_mfma<128, 2, true><<<GB, 256, 0, stream>>>(x, wt1, AS[0], AD[0],
                                                    (unsigned short*)hq, es, ed, pself, flags);
    pexp_kernel<2><<<EB, 256, 0, stream>>>(es, ed, csr2, edata);
    attn_kernel<2><<<AB, 256, 0, stream>>>(hq, edata, pself, row_ptr, B[0], buf1b, flags);
    // layers 2..4 (H=1, K=96)
    unsigned short* wts[3] = {wt2, wt3, wt4};
    for (int l = 1; l < 4; l++){
        gemm_mfma<96, 1, false><<<GB, 256, 0, stream>>>(buf1b, wts[l - 1], AS[l], AD[l],
                                                        (unsigned short*)hq, es, ed, pself, flags);
        pexp_kernel<1><<<EB, 256, 0, stream>>>(es, ed, csr2, edata);
        attn_kernel<1><<<AB, 256, 0, stream>>>(hq, edata, pself, row_ptr, B[l], buf1b, flags);
    }

    pool_kernel<<<(NN + 31) / 32, 64, 0, stream>>>(buf1b, batch, pooled, gcnt, flags);
    final_kernel<<<1, 64, 0, stream>>>(pooled, gcnt, Wc, bc, d_out, flags);
}